// Round 1
// baseline (429.392 us; speedup 1.0000x reference)
//
#include <hip/hip_runtime.h>
#include <hip/hip_bf16.h>

// out = A @ b, A sparse COO (rows, cols, vals), N=50000, E=1.6M, D=128, fp32.
// Strategy: build CSR on-device (hist -> scan -> scatter), then one wave per
// row accumulates D=128 in registers (float2 per lane) and writes coalesced.

#define D_DIM 128

// ---------------- histogram ----------------
__global__ __launch_bounds__(256) void hist_kernel(const int* __restrict__ rows,
                                                   int* __restrict__ hist, int E) {
    int e = blockIdx.x * 256 + threadIdx.x;
    if (e < E) atomicAdd(&hist[rows[e]], 1);
}

// ---------------- exclusive scan (single block) ----------------
__global__ __launch_bounds__(1024) void scan_kernel(const int* __restrict__ hist,
                                                    int* __restrict__ row_start,
                                                    int* __restrict__ cursor, int n) {
    __shared__ int wsum[16];
    __shared__ int carry_s;
    const int tid  = threadIdx.x;
    const int lane = tid & 63;
    const int wid  = tid >> 6;
    if (tid == 0) carry_s = 0;
    __syncthreads();
    for (int base = 0; base < n; base += 1024) {
        int i = base + tid;
        int v = (i < n) ? hist[i] : 0;
        int x = v;
        #pragma unroll
        for (int off = 1; off < 64; off <<= 1) {
            int y = __shfl_up(x, off, 64);
            if (lane >= off) x += y;
        }
        if (lane == 63) wsum[wid] = x;
        __syncthreads();
        int wpre = 0;
        for (int w = 0; w < wid; ++w) wpre += wsum[w];
        int excl = carry_s + wpre + x - v;
        if (i < n) { row_start[i] = excl; cursor[i] = excl; }
        __syncthreads();
        if (tid == 1023) carry_s = carry_s + wpre + x;
        __syncthreads();
    }
    if (tid == 0) row_start[n] = carry_s;
}

// ---------------- scatter into CSR order (packed col+val) ----------------
__global__ __launch_bounds__(256) void scatter_kernel(const int* __restrict__ rows,
                                                      const int* __restrict__ cols,
                                                      const float* __restrict__ vals,
                                                      int* __restrict__ cursor,
                                                      int2* __restrict__ edges, int E) {
    int e = blockIdx.x * 256 + threadIdx.x;
    if (e >= E) return;
    int r   = rows[e];
    int pos = atomicAdd(&cursor[r], 1);
    edges[pos] = make_int2(cols[e], __float_as_int(vals[e]));
}

// ---------------- per-row reduce: one wave per row ----------------
__global__ __launch_bounds__(256) void reduce_kernel(const int* __restrict__ row_start,
                                                     const int2* __restrict__ edges,
                                                     const float* __restrict__ b,
                                                     float* __restrict__ out, int n) {
    const int lane = threadIdx.x & 63;
    const int row  = blockIdx.x * 4 + (threadIdx.x >> 6);
    if (row >= n) return;
    int s    = __builtin_amdgcn_readfirstlane(row_start[row]);
    int eend = __builtin_amdgcn_readfirstlane(row_start[row + 1]);
    float2 acc = make_float2(0.f, 0.f);
    for (int base = s; base < eend; base += 64) {
        int cnt = eend - base; if (cnt > 64) cnt = 64;
        int2 cv = make_int2(0, 0);
        if (lane < cnt) cv = edges[base + lane];
        for (int j = 0; j < cnt; ++j) {
            int   col = __shfl(cv.x, j, 64);
            float val = __int_as_float(__shfl(cv.y, j, 64));
            const float2 brow =
                *reinterpret_cast<const float2*>(b + (size_t)col * D_DIM + lane * 2);
            acc.x = fmaf(val, brow.x, acc.x);
            acc.y = fmaf(val, brow.y, acc.y);
        }
    }
    *reinterpret_cast<float2*>(out + (size_t)row * D_DIM + lane * 2) = acc;
}

// ---------------- fallback: pure atomic path (if ws too small) ----------------
__global__ __launch_bounds__(256) void zero_kernel(float* __restrict__ out, size_t n4) {
    size_t i = (size_t)blockIdx.x * 256 + threadIdx.x;
    size_t stride = (size_t)gridDim.x * 256;
    for (; i < n4; i += stride)
        reinterpret_cast<float4*>(out)[i] = make_float4(0.f, 0.f, 0.f, 0.f);
}

__global__ __launch_bounds__(256) void atomic_spmm_kernel(const int* __restrict__ rows,
                                                          const int* __restrict__ cols,
                                                          const float* __restrict__ vals,
                                                          const float* __restrict__ b,
                                                          float* __restrict__ out, int E) {
    long long t = (long long)blockIdx.x * 256 + threadIdx.x;
    int e = (int)(t >> 5);
    int q = (int)(t & 31);
    if (e >= E) return;
    int   r = rows[e];
    int   c = cols[e];
    float v = vals[e];
    float4 bb = *reinterpret_cast<const float4*>(b + (size_t)c * D_DIM + q * 4);
    float* o = out + (size_t)r * D_DIM + q * 4;
    atomicAdd(o + 0, v * bb.x);
    atomicAdd(o + 1, v * bb.y);
    atomicAdd(o + 2, v * bb.z);
    atomicAdd(o + 3, v * bb.w);
}

extern "C" void kernel_launch(void* const* d_in, const int* in_sizes, int n_in,
                              void* d_out, int out_size, void* d_ws, size_t ws_size,
                              hipStream_t stream) {
    const int*   idx  = (const int*)d_in[0];   // [2, E] flat int32
    const float* vals = (const float*)d_in[1]; // [E]
    const float* b    = (const float*)d_in[3]; // [N, 128]
    float*       out  = (float*)d_out;

    const int E = in_sizes[1];
    const int N = in_sizes[3] / D_DIM;
    const int* rows = idx;
    const int* cols = idx + E;

    // ws layout: row_start[N+1] | hist[N] | cursor[N] | edges[E] (int2, 8B aligned)
    size_t int_bytes  = (size_t)(3 * N + 1) * sizeof(int);
    size_t edges_off  = (int_bytes + 7) & ~(size_t)7;
    size_t need       = edges_off + (size_t)E * sizeof(int2);

    if (ws_size >= need) {
        char* ws        = (char*)d_ws;
        int*  row_start = (int*)ws;
        int*  hist      = row_start + (N + 1);
        int*  cursor    = hist + N;
        int2* edges     = (int2*)(ws + edges_off);

        hipMemsetAsync(hist, 0, (size_t)N * sizeof(int), stream);

        int eb = (E + 255) / 256;
        hist_kernel<<<eb, 256, 0, stream>>>(rows, hist, E);
        scan_kernel<<<1, 1024, 0, stream>>>(hist, row_start, cursor, N);
        scatter_kernel<<<eb, 256, 0, stream>>>(rows, cols, vals, cursor, edges, E);
        int rb = (N + 3) / 4;
        reduce_kernel<<<rb, 256, 0, stream>>>(row_start, edges, b, out, N);
    } else {
        // Fallback: zero + atomic scatter-add
        size_t n4 = (size_t)N * D_DIM / 4;
        zero_kernel<<<2048, 256, 0, stream>>>(out, n4);
        long long total = (long long)E * 32;
        int ab = (int)((total + 255) / 256);
        atomic_spmm_kernel<<<ab, 256, 0, stream>>>(rows, cols, vals, b, out, E);
    }
}